// Round 5
// baseline (655.671 us; speedup 1.0000x reference)
//
#include <hip/hip_runtime.h>
#include <math.h>

// SwinTransformerBlock: B=16,H=W=64,E=32,WD=8 -> NW=64, D=2048
#define ROWS 1024
#define DIM  2048
#define FFDIM 8192
#define NHEAD 8
#define HD 256
#define NWIN 64
#define MB (1u << 20)

typedef __attribute__((ext_vector_type(8))) short short8;   // 8 bf16
typedef __attribute__((ext_vector_type(4))) float f32x4;
typedef unsigned int uint32;
typedef unsigned short ushort_t;

#define MFMA16(a, b, c) __builtin_amdgcn_mfma_f32_16x16x32_bf16((a), (b), (c), 0, 0, 0)
// 16B-slot XOR swizzle within a 64B LDS row (verified: 0 bank conflicts in r3)
#define SWZ(r) (((r) >> 1) & 3)

__device__ __forceinline__ ushort_t rne(float x) {          // fp32 -> bf16 RNE
  uint32 u = __float_as_uint(x);
  return (ushort_t)((u + 0x7FFFu + ((u >> 16) & 1u)) >> 16);
}
__device__ __forceinline__ float bf2f(ushort_t h) {
  return __uint_as_float(((uint32)h) << 16);
}

// ---------------------------------------------------------------------------
// Transpose-convert: src fp32 [R][C] -> dst bf16 [C][R] (RNE). 64x64 tiles.
// grid (C/64, R/64, nmat); src selected by z, dst offset z*R*C.
__global__ __launch_bounds__(256)
void wconvT_kernel(const float* __restrict__ s0, const float* __restrict__ s1,
                   const float* __restrict__ s2, ushort_t* __restrict__ d,
                   int R, int C) {
  const float* src = (blockIdx.z == 0) ? s0 : (blockIdx.z == 1) ? s1 : s2;
  ushort_t* dst = d + (size_t)blockIdx.z * R * C;
  __shared__ float tl[64][65];
  const int r0 = blockIdx.y * 64, c0 = blockIdx.x * 64;
  const int tr = threadIdx.x >> 4, tc = threadIdx.x & 15;
#pragma unroll
  for (int i = 0; i < 4; ++i) {
    const int r = tr + i * 16;
    float4 v = *(const float4*)&src[(size_t)(r0 + r) * C + c0 + tc * 4];
    tl[r][tc * 4 + 0] = v.x; tl[r][tc * 4 + 1] = v.y;
    tl[r][tc * 4 + 2] = v.z; tl[r][tc * 4 + 3] = v.w;
  }
  __syncthreads();
#pragma unroll
  for (int i = 0; i < 4; ++i) {
    const int c = tr + i * 16;   // source col == dst row
    ushort4 o;
    o.x = rne(tl[tc * 4 + 0][c]); o.y = rne(tl[tc * 4 + 1][c]);
    o.z = rne(tl[tc * 4 + 2][c]); o.w = rne(tl[tc * 4 + 3][c]);
    *(ushort4*)&dst[(size_t)(c0 + c) * R + r0 + tc * 4] = o;
  }
}

// ---------------------------------------------------------------------------
// bf16 MFMA GEMM. A bf16 [M][K] row-major, Bt bf16 [N][K] (pre-transposed).
// Block: 256 thr = 4 waves (2x2). Tile BM=MI*32 x 128, BK=32.
// EPI: 0 = +bias -> bf16 out; 1 = +bias,GELU -> bf16 out; 3 = raw fp32 partial
template <int MI, int EPI>
__device__ __forceinline__ void gemm_body(
    const ushort_t* __restrict__ A, const ushort_t* __restrict__ Bt,
    const float* __restrict__ bias, float* __restrict__ Cf,
    ushort_t* __restrict__ C16, int N, int K, int kbeg, int kend,
    int m0, int n0, short* As, short* Bs) {
  const int t = threadIdx.x;
  const int lane = t & 63;
  const int wid = t >> 6;
  const int wr = wid >> 1, wc = wid & 1;
  const int l15 = lane & 15, l4 = lane >> 4;
  constexpr int ACH = MI / 2;                 // A 16B-chunks per thread

  f32x4 acc[MI][4];
#pragma unroll
  for (int i = 0; i < MI; ++i)
#pragma unroll
    for (int j = 0; j < 4; ++j) {
      f32x4 z = {0.f, 0.f, 0.f, 0.f};
      acc[i][j] = z;
    }

  // fragment LDS byte offsets (loop-invariant)
  int aoff[MI], boff[4];
#pragma unroll
  for (int mi = 0; mi < MI; ++mi) {
    int m = wr * MI * 16 + mi * 16 + l15;
    aoff[mi] = m * 64 + ((l4 ^ SWZ(m)) << 4);
  }
#pragma unroll
  for (int ni = 0; ni < 4; ++ni) {
    int n = wc * 64 + ni * 16 + l15;
    boff[ni] = n * 64 + ((l4 ^ SWZ(n)) << 4);
  }

  // staging: chunk cid = t + j*256 -> row = cid>>2, k-slot q = t&3 (16B = 8 bf16)
  const int srow = t >> 2, sq = t & 3;
  const ushort_t* aptr = A + (size_t)(m0 + srow) * K + sq * 8;
  const ushort_t* bptr = Bt + (size_t)(n0 + srow) * K + sq * 8;
  int awoff[ACH], bwoff[2];
#pragma unroll
  for (int j = 0; j < ACH; ++j) {
    const int row = srow + j * 64;
    awoff[j] = row * 64 + ((sq ^ SWZ(row)) << 4);
  }
#pragma unroll
  for (int j = 0; j < 2; ++j) {
    const int row = srow + j * 64;
    bwoff[j] = row * 64 + ((sq ^ SWZ(row)) << 4);
  }

  // prologue loads
  uint4 pa[ACH], pb[2];
#pragma unroll
  for (int j = 0; j < ACH; ++j)
    pa[j] = *(const uint4*)(aptr + (size_t)(j * 64) * K + kbeg);
#pragma unroll
  for (int j = 0; j < 2; ++j)
    pb[j] = *(const uint4*)(bptr + (size_t)(j * 64) * K + kbeg);

  for (int k0 = kbeg; k0 < kend; k0 += 32) {
    __syncthreads();                            // prev tile reads done
#pragma unroll
    for (int j = 0; j < ACH; ++j) *(uint4*)((char*)As + awoff[j]) = pa[j];
#pragma unroll
    for (int j = 0; j < 2; ++j)   *(uint4*)((char*)Bs + bwoff[j]) = pb[j];
    __syncthreads();                            // tile ready

    if (k0 + 32 < kend) {                       // prefetch next (hides under MFMA)
#pragma unroll
      for (int j = 0; j < ACH; ++j)
        pa[j] = *(const uint4*)(aptr + (size_t)(j * 64) * K + (k0 + 32));
#pragma unroll
      for (int j = 0; j < 2; ++j)
        pb[j] = *(const uint4*)(bptr + (size_t)(j * 64) * K + (k0 + 32));
    }

    short8 a[MI], b4[4];
#pragma unroll
    for (int mi = 0; mi < MI; ++mi)
      a[mi] = *(const short8*)((const char*)As + aoff[mi]);
#pragma unroll
    for (int ni = 0; ni < 4; ++ni)
      b4[ni] = *(const short8*)((const char*)Bs + boff[ni]);
#pragma unroll
    for (int mi = 0; mi < MI; ++mi)
#pragma unroll
      for (int ni = 0; ni < 4; ++ni)
        acc[mi][ni] = MFMA16(a[mi], b4[ni], acc[mi][ni]);
  }

  // epilogue: C row = l4*4 + r, col = l15 (r3-verified mapping)
#pragma unroll
  for (int ni = 0; ni < 4; ++ni) {
    const int n = n0 + wc * 64 + ni * 16 + l15;
    const float bb = (EPI == 3) ? 0.f : bias[n];
#pragma unroll
    for (int mi = 0; mi < MI; ++mi) {
      const int mbase = m0 + wr * MI * 16 + mi * 16 + l4 * 4;
#pragma unroll
      for (int r = 0; r < 4; ++r) {
        float x = acc[mi][ni][r] + bb;
        const size_t idx = (size_t)(mbase + r) * N + n;
        if (EPI == 0) {
          C16[idx] = rne(x);
        } else if (EPI == 1) {
          x = 0.5f * x * (1.0f + erff(x * 0.70710678118654752f));
          C16[idx] = rne(x);
        } else {
          Cf[idx] = x;
        }
      }
    }
  }
}

template <int MI, int EPI>
__global__ __launch_bounds__(256, 2)
void gemm_k(const ushort_t* __restrict__ A, const ushort_t* __restrict__ Bt,
            const float* __restrict__ bias, float* __restrict__ Cf,
            ushort_t* __restrict__ C16, int N, int K, int ksplit) {
  __shared__ __align__(16) short As[MI * 1024];
  __shared__ __align__(16) short Bs[4096];
  const int kbeg = blockIdx.z * ksplit;
  float* Cfe = (EPI == 3) ? Cf + (size_t)blockIdx.z * ROWS * N : Cf;
  gemm_body<MI, EPI>(A, Bt, bias, Cfe, C16, N, K, kbeg, kbeg + ksplit,
                     blockIdx.y * MI * 32, blockIdx.x * 128, As, Bs);
}

// QKV fused: grid (48, 16): 3 mats x 16 n-tiles, BM=64 -> 768 blocks (3/CU)
__global__ __launch_bounds__(256, 3)
void qkv_k(const ushort_t* __restrict__ A, const ushort_t* __restrict__ qkvT,
           const float* __restrict__ bq, const float* __restrict__ bk,
           const float* __restrict__ bv, ushort_t* __restrict__ outq) {
  __shared__ __align__(16) short As[2048];
  __shared__ __align__(16) short Bs[4096];
  const int nb = blockIdx.x;
  const int mat = nb >> 4;
  const ushort_t* W = qkvT + (size_t)mat * DIM * DIM;
  const float* B = (mat == 0) ? bq : (mat == 1) ? bk : bv;
  ushort_t* out = outq + (size_t)mat * ROWS * DIM;
  gemm_body<2, 0>(A, W, B, nullptr, out, DIM, DIM, 0, DIM,
                  blockIdx.y * 64, (nb & 15) * 128, As, Bs);
}

// split-K reduce for FFN2: out = sum_s p[s] + bias + R
__global__ __launch_bounds__(256)
void reduce4_kernel(const float* __restrict__ p, const float* __restrict__ bias,
                    const float* __restrict__ R, float* __restrict__ out) {
  const int idx = blockIdx.x * 256 + threadIdx.x;       // float4 index
  const size_t PS = (size_t)ROWS * DIM / 4;
  const float4* p4 = (const float4*)p;
  float4 s0 = p4[idx], s1 = p4[idx + PS], s2 = p4[idx + 2 * PS], s3 = p4[idx + 3 * PS];
  const int n = (idx & (DIM / 4 - 1)) * 4;
  float4 bi = *(const float4*)&bias[n];
  float4 rr = ((const float4*)R)[idx];
  float4 o;
  o.x = s0.x + s1.x + s2.x + s3.x + bi.x + rr.x;
  o.y = s0.y + s1.y + s2.y + s3.y + bi.y + rr.y;
  o.z = s0.z + s1.z + s2.z + s3.z + bi.z + rr.z;
  o.w = s0.w + s1.w + s2.w + s3.w + bi.w + rr.w;
  ((float4*)out)[idx] = o;
}

// ---------------------------------------------------------------------------
__device__ inline void block_stats(float s, float ss, float& mean, float& rstd) {
#pragma unroll
  for (int off = 32; off; off >>= 1) {
    s  += __shfl_xor(s,  off);
    ss += __shfl_xor(ss, off);
  }
  __shared__ float red[8];
  const int t = threadIdx.x;
  const int w = t >> 6;
  if ((t & 63) == 0) { red[w] = s; red[4 | w] = ss; }
  __syncthreads();
  s  = red[0] + red[1] + red[2] + red[3];
  ss = red[4] + red[5] + red[6] + red[7];
  mean = s * (1.0f / DIM);
  float var = ss * (1.0f / DIM) - mean * mean;
  rstd = 1.0f / sqrtf(var + 1e-5f);
}

// window partition gather + LN1 -> windows fp32 + xbf bf16
__global__ __launch_bounds__(256)
void partition_ln1_kernel(const float* __restrict__ emb,
                          const float* __restrict__ g, const float* __restrict__ be,
                          float* __restrict__ windows, ushort_t* __restrict__ xbf) {
  const int row = blockIdx.x;
  const int b = row >> 6, n = row & 63;
  const int vw = n >> 3, hw = n & 7;
  const int t = threadIdx.x;
  const int d0 = t * 4, d1 = d0 + 1024;

  const int vp0 = d0 >> 8, hp0 = (d0 >> 5) & 7, e0 = d0 & 31;
  const int vp1 = d1 >> 8, hp1 = (d1 >> 5) & 7, e1 = d1 & 31;
  float4 v0 = *(const float4*)&emb[(size_t)(((b*64 + vp0*8 + vw)*64) + hp0*8 + hw)*32 + e0];
  float4 v1 = *(const float4*)&emb[(size_t)(((b*64 + vp1*8 + vw)*64) + hp1*8 + hw)*32 + e1];

  float s  = v0.x+v0.y+v0.z+v0.w + v1.x+v1.y+v1.z+v1.w;
  float ss = v0.x*v0.x+v0.y*v0.y+v0.z*v0.z+v0.w*v0.w
           + v1.x*v1.x+v1.y*v1.y+v1.z*v1.z+v1.w*v1.w;
  float mean, rstd;
  block_stats(s, ss, mean, rstd);

  float* wrow = windows + (size_t)row * DIM;
  *(float4*)&wrow[d0] = v0;
  *(float4*)&wrow[d1] = v1;

  float4 g0 = *(const float4*)&g[d0],  g1 = *(const float4*)&g[d1];
  float4 b0 = *(const float4*)&be[d0], b1 = *(const float4*)&be[d1];
  ushort4 o0, o1;
  o0.x = rne((v0.x-mean)*rstd*g0.x + b0.x); o0.y = rne((v0.y-mean)*rstd*g0.y + b0.y);
  o0.z = rne((v0.z-mean)*rstd*g0.z + b0.z); o0.w = rne((v0.w-mean)*rstd*g0.w + b0.w);
  o1.x = rne((v1.x-mean)*rstd*g1.x + b1.x); o1.y = rne((v1.y-mean)*rstd*g1.y + b1.y);
  o1.z = rne((v1.z-mean)*rstd*g1.z + b1.z); o1.w = rne((v1.w-mean)*rstd*g1.w + b1.w);
  *(ushort4*)&xbf[(size_t)row * DIM + d0] = o0;
  *(ushort4*)&xbf[(size_t)row * DIM + d1] = o1;
}

// LN2: fp32 in -> bf16 out
__global__ __launch_bounds__(256)
void ln_kernel(const float* __restrict__ in, const float* __restrict__ g,
               const float* __restrict__ be, ushort_t* __restrict__ out) {
  const int row = blockIdx.x;
  const int t = threadIdx.x;
  const float* x = in + (size_t)row * DIM;
  const int d0 = t * 4, d1 = d0 + 1024;
  float4 v0 = *(const float4*)&x[d0];
  float4 v1 = *(const float4*)&x[d1];
  float s  = v0.x+v0.y+v0.z+v0.w + v1.x+v1.y+v1.z+v1.w;
  float ss = v0.x*v0.x+v0.y*v0.y+v0.z*v0.z+v0.w*v0.w
           + v1.x*v1.x+v1.y*v1.y+v1.z*v1.z+v1.w*v1.w;
  float mean, rstd;
  block_stats(s, ss, mean, rstd);
  float4 g0 = *(const float4*)&g[d0],  g1 = *(const float4*)&g[d1];
  float4 b0 = *(const float4*)&be[d0], b1 = *(const float4*)&be[d1];
  ushort4 o0, o1;
  o0.x = rne((v0.x-mean)*rstd*g0.x + b0.x); o0.y = rne((v0.y-mean)*rstd*g0.y + b0.y);
  o0.z = rne((v0.z-mean)*rstd*g0.z + b0.z); o0.w = rne((v0.w-mean)*rstd*g0.w + b0.w);
  o1.x = rne((v1.x-mean)*rstd*g1.x + b1.x); o1.y = rne((v1.y-mean)*rstd*g1.y + b1.y);
  o1.z = rne((v1.z-mean)*rstd*g1.z + b1.z); o1.w = rne((v1.w-mean)*rstd*g1.w + b1.w);
  *(ushort4*)&out[(size_t)row * DIM + d0] = o0;
  *(ushort4*)&out[(size_t)row * DIM + d1] = o1;
}

// ---------------------------------------------------------------------------
// Attention: one block per (b, head, query-half). q/k/v are bf16; math fp32.
// QK register-blocked 2 rows x 4 keys; PV with hoisted V row reads.
__global__ __launch_bounds__(256)
void attn_kernel(const ushort_t* __restrict__ Q, const ushort_t* __restrict__ K,
                 const ushort_t* __restrict__ V, const float* __restrict__ pb,
                 const float* __restrict__ windows, float* __restrict__ attn_out) {
  __shared__ __align__(16) float kv[NWIN][264];   // K then V; padded stride
  __shared__ __align__(16) float qs[32][268];
  __shared__ float att[32][NWIN + 1];
  const int blk = blockIdx.x;
  const int bh = blk >> 1, half = blk & 1;
  const int b = bh >> 3, h = bh & 7;
  const int qbase = half * 32;
  const int t = threadIdx.x;
  const size_t base = (size_t)b * 64 * DIM + (size_t)h * HD;   // element index

  // stage K [64][256] and Q-half [32][256], bf16 -> fp32
#pragma unroll
  for (int j = 0; j < 8; ++j) {
    int idx = t + j * 256;          // 8-elem chunk id
    int m = idx >> 5, c8 = idx & 31;
    uint4 raw = *(const uint4*)&K[base + (size_t)m * DIM + c8 * 8];
    float4 f0 = {bf2f((ushort_t)(raw.x & 0xffff)), bf2f((ushort_t)(raw.x >> 16)),
                 bf2f((ushort_t)(raw.y & 0xffff)), bf2f((ushort_t)(raw.y >> 16))};
    float4 f1 = {bf2f((ushort_t)(raw.z & 0xffff)), bf2f((ushort_t)(raw.z >> 16)),
                 bf2f((ushort_t)(raw.w & 0xffff)), bf2f((ushort_t)(raw.w >> 16))};
    *(float4*)&kv[m][c8 * 8] = f0;
    *(float4*)&kv[m][c8 * 8 + 4] = f1;
  }
#pragma unroll
  for (int j = 0; j < 4; ++j) {
    int idx = t + j * 256;
    int m = idx >> 5, c8 = idx & 31;
    uint4 raw = *(const uint4*)&Q[base + (size_t)(qbase + m) * DIM + c8 * 8];
    float4 f0 = {bf2f((ushort_t)(raw.x & 0xffff)), bf2f((ushort_t)(raw.x >> 16)),
                 bf2f((ushort_t)(raw.y & 0xffff)), bf2f((ushort_t)(raw.y >> 16))};
    float4 f1 = {bf2f((ushort_t)(raw.z & 0xffff)), bf2f((ushort_t)(raw.z >> 16)),
                 bf2f((ushort_t)(raw.w & 0xffff)), bf2f((ushort_t)(raw.w >> 16))};
    *(float4*)&qs[m][c8 * 8] = f0;
    *(float4*)&qs[m][c8 * 8 + 4] = f1;
  }
  __syncthreads();

  // logits: thread = (row pair rp, key group kg of 4): rows {rp, rp+16}
  {
    const int rp = t & 15;
    const int kg = t >> 4;          // 0..15
    float acc[2][4] = {};
    for (int dg = 0; dg < 64; ++dg) {
      float4 q0 = *(const float4*)&qs[rp][dg * 4];
      float4 q1 = *(const float4*)&qs[rp + 16][dg * 4];
#pragma unroll
      for (int j = 0; j < 4; ++j) {
        float4 kr = *(const float4*)&kv[4 * kg + j][dg * 4];
        acc[0][j] += q0.x * kr.x + q0.y * kr.y + q0.z * kr.z + q0.w * kr.w;
        acc[1][j] += q1.x * kr.x + q1.y * kr.y + q1.z * kr.z + q1.w * kr.w;
      }
    }
    const float scale = 0.022097086912079608f;  // 1/sqrt(2048)
#pragma unroll
    for (int i = 0; i < 2; ++i) {
      const int rl = rp + i * 16;
      const int gr = qbase + rl;
#pragma unroll
      for (int j = 0; j < 4; ++j) {
        const int m = 4 * kg + j;
        float l = acc[i][j] * scale + pb[gr * 64 + m];
        if (m == gr) l = -INFINITY;
        att[rl][m] = l;
      }
    }
  }
  __syncthreads();

  // V stage (all threads) overlapped with softmax (threads < 32)
#pragma unroll
  for (int j = 0; j < 8; ++j) {
    int idx = t + j * 256;
    int m = idx >> 5, c8 = idx & 31;
    uint4 raw = *(const uint4*)&V[base + (size_t)m * DIM + c8 * 8];
    float4 f0 = {bf2f((ushort_t)(raw.x & 0xffff)), bf2f((ushort_t)(raw.x >> 16)),
                 bf2f((ushort_t)(raw.y & 0xffff)), bf2f((ushort_t)(raw.y >> 16))};
    float4 f1 = {bf2f((ushort_t)(raw.z & 0xffff)), bf2f((ushort_t)(raw.z >> 16)),
                 bf2f((ushort_t)(raw.w & 0xffff)), bf2f((ushort_t)(raw.w >> 16))};
    *(float4*)&kv[m][c8 * 8] = f0;
    *(float4*)&kv[m][c8 * 8 + 4] = f1;
  }
  if (t < 32) {
    float mx = -INFINITY;
#pragma unroll
    for (int m = 0; m < 64; ++m) mx = fmaxf(mx, att[t][m]);
    float sum = 0.f;
#pragma unroll
    for (int m = 0; m < 64; ++m) {
      float e = expf(att[t][m] - mx);
      att[t][m] = e;
      sum += e;
    }
    float inv = 1.0f / sum;
#pragma unroll
    for (int m = 0; m < 64; ++m) att[t][m] *= inv;
  }
  __syncthreads();

  // PV + residual: thread = (dg = t&63, row group rg of 8); V row hoisted
  {
    const int dg = t & 63, rg = t >> 6;
    float4 s[8];
#pragma unroll
    for (int i = 0; i < 8; ++i) s[i] = make_float4(0.f, 0.f, 0.f, 0.f);
    for (int m = 0; m < 64; ++m) {
      float4 vr = *(const float4*)&kv[m][dg * 4];
#pragma unroll
      for (int i = 0; i < 8; ++i) {
        const float a = att[rg * 8 + i][m];
        s[i].x = fmaf(a, vr.x, s[i].x); s[i].y = fmaf(a, vr.y, s[i].y);
        s[i].z = fmaf(a, vr.z, s[i].z); s[i].w = fmaf(a, vr.w, s[i].w);
      }
    }
#pragma unroll
    for (int i = 0; i < 8; ++i) {
      const int row = qbase + rg * 8 + i;
      const size_t o = base + (size_t)row * DIM + dg * 4;
      float4 w4 = *(const float4*)&windows[o];
      float4 r;
      r.x = s[i].x + w4.x; r.y = s[i].y + w4.y;
      r.z = s[i].z + w4.z; r.w = s[i].w + w4.w;
      *(float4*)&attn_out[o] = r;
    }
  }
}

// ---------------------------------------------------------------------------
extern "C" void kernel_launch(void* const* d_in, const int* in_sizes, int n_in,
                              void* d_out, int out_size, void* d_ws, size_t ws_size,
                              hipStream_t stream) {
  const float* emb  = (const float*)d_in[0];
  const float* ln1g = (const float*)d_in[1];
  const float* ln1b = (const float*)d_in[2];
  const float* wq   = (const float*)d_in[3];
  const float* bq   = (const float*)d_in[4];
  const float* wk   = (const float*)d_in[5];
  const float* bk   = (const float*)d_in[6];
  const float* wv   = (const float*)d_in[7];
  const float* bv   = (const float*)d_in[8];
  const float* pb   = (const float*)d_in[9];
  const float* ln2g = (const float*)d_in[10];
  const float* ln2b = (const float*)d_in[11];
  const float* w1   = (const float*)d_in[12];
  const float* b1   = (const float*)d_in[13];
  const float* w2   = (const float*)d_in[14];
  const float* b2   = (const float*)d_in[15];
  float* out = (float*)d_out;

  // workspace layout (112 MB total), offsets in bytes:
  //  [0,8)    windows fp32            (dead after attn; reused by partial)
  //  [8,12)   xbf bf16 (LN1), then x2bf (LN2)
  //  [12,44)  w1T bf16 [8192][2048]
  //  [44,56)  qb/kb/vb bf16
  //  [56,64)  attn_out fp32
  //  [64,88)  qkvT bf16 (dead after QKV) -> [64,96) w2T bf16 (conv after attn)
  //  [96,112) ffh bf16 [1024][8192]
  //  [0,32)   partial fp32 x4 (FFN2 split-K; windows/xbf/w1T dead by then)
  char* W8 = (char*)d_ws;
  float*    windows  = (float*)(W8 + (size_t)0 * MB);
  ushort_t* xbf      = (ushort_t*)(W8 + (size_t)8 * MB);
  ushort_t* w1T      = (ushort_t*)(W8 + (size_t)12 * MB);
  ushort_t* qb       = (ushort_t*)(W8 + (size_t)44 * MB);
  float*    attn_out = (float*)(W8 + (size_t)56 * MB);
  ushort_t* qkvT     = (ushort_t*)(W8 + (size_t)64 * MB);
  ushort_t* w2T      = (ushort_t*)(W8 + (size_t)64 * MB);
  ushort_t* ffh      = (ushort_t*)(W8 + (size_t)96 * MB);
  float*    partial  = (float*)(W8 + (size_t)0 * MB);
  const size_t OFF = (size_t)ROWS * DIM;

  // weight transpose-converts (w2 deferred until qkvT is dead)
  wconvT_kernel<<<dim3(32, 32, 3), 256, 0, stream>>>(wq, wk, wv, qkvT, DIM, DIM);
  wconvT_kernel<<<dim3(128, 32, 1), 256, 0, stream>>>(w1, w1, w1, w1T, DIM, FFDIM);

  partition_ln1_kernel<<<ROWS, 256, 0, stream>>>(emb, ln1g, ln1b, windows, xbf);

  // QKV: 3x [1024,2048]x[2048,2048], BM=64 -> 768 blocks (3/CU)
  qkv_k<<<dim3(48, 16), 256, 0, stream>>>(xbf, qkvT, bq, bk, bv, qb);

  attn_kernel<<<16 * NHEAD * 2, 256, 0, stream>>>(qb, qb + OFF, qb + 2 * OFF, pb,
                                                  windows, attn_out);

  wconvT_kernel<<<dim3(32, 128, 1), 256, 0, stream>>>(w2, w2, w2, w2T, FFDIM, DIM);

  ln_kernel<<<ROWS, 256, 0, stream>>>(attn_out, ln2g, ln2b, xbf);

  // FFN1: [1024,2048]x[2048,8192] + GELU -> bf16, 512 blocks (2/CU)
  gemm_k<4, 1><<<dim3(64, 8, 1), 256, 0, stream>>>(
      xbf, w1T, b1, nullptr, ffh, FFDIM, DIM, DIM);
  // FFN2: [1024,8192]x[8192,2048], split-K=4 -> 512 blocks, raw fp32 partials
  gemm_k<4, 3><<<dim3(16, 8, 4), 256, 0, stream>>>(
      ffh, w2T, nullptr, partial, nullptr, DIM, FFDIM, FFDIM / 4);
  // out = sum(partials) + b2 + attn_out
  reduce4_kernel<<<(ROWS * DIM / 4) / 256, 256, 0, stream>>>(partial, b2, attn_out, out);
}

// Round 8
// 544.404 us; speedup vs baseline: 1.2044x; 1.2044x over previous
//
#include <hip/hip_runtime.h>
#include <math.h>

// SwinTransformerBlock: B=16,H=W=64,E=32,WD=8 -> NW=64, D=2048
#define ROWS 1024
#define DIM  2048
#define FFDIM 8192
#define NHEAD 8
#define HD 256
#define NWIN 64
#define MB (1u << 20)

typedef __attribute__((ext_vector_type(8))) short short8;   // 8 bf16
typedef __attribute__((ext_vector_type(4))) float f32x4;
typedef unsigned int uint32;
typedef unsigned short ushort_t;

#define MFMA16(a, b, c) __builtin_amdgcn_mfma_f32_16x16x32_bf16((a), (b), (c), 0, 0, 0)

// async global->LDS DMA, 16B per lane: LDS dest = uniform base + lane*16,
// global src = per-lane address (guide m97/m104 semantics)
#define GLOAD(g, l)                                                          \
  __builtin_amdgcn_global_load_lds(                                          \
      (const __attribute__((address_space(1))) unsigned int*)(g),            \
      (__attribute__((address_space(3))) unsigned int*)(l), 16, 0, 0)

__device__ __forceinline__ ushort_t rne(float x) {          // fp32 -> bf16 RNE
  uint32 u = __float_as_uint(x);
  return (ushort_t)((u + 0x7FFFu + ((u >> 16) & 1u)) >> 16);
}
__device__ __forceinline__ float bf2f(ushort_t h) {
  return __uint_as_float(((uint32)h) << 16);
}
// XCD-chunked bijective swizzle (nwg % 8 == 0)
__device__ __forceinline__ int swz8(int id, int nwg) {
  const int c = nwg >> 3;
  return (id & 7) * c + (id >> 3);
}

// ---------------------------------------------------------------------------
// m97-style bf16 MFMA GEMM body. A bf16 [M][K], Bt bf16 [N][K] pre-transposed.
// Tile 64(M) x 128(N), BK=32. 256 thr = 4 waves (2x2); wave = 32x64 out,
// 2x4 frags of 16x16, 8 MFMA/iter. LDS k-slot-major: chunk(kslot,row) at
// (kslot*NR + row)*16B -> frag ds_read_b128 is 256B-contiguous per 1/4-wave
// (2-way bank alias = free). Staging: global_load_lds, 3 calls/wave/iter.
// Double-buffered; one barrier (with vmcnt drain) per K-step.
// EPI: 0 = +bias -> bf16; 1 = +bias,GELU -> bf16; 3 = raw fp32 partial
template <int EPI>
__device__ __forceinline__ void gbody(
    const ushort_t* __restrict__ A, const ushort_t* __restrict__ Bt,
    const float* __restrict__ bias, float* __restrict__ Cf,
    ushort_t* __restrict__ C16, int N, int K, int kbeg, int kend,
    int m0, int n0, short* As, short* Bs) {
  const int t = threadIdx.x;
  const int lane = t & 63, wid = t >> 6;
  const int wr = wid >> 1, wc = wid & 1;
  const int l15 = lane & 15, l4 = lane >> 4;

  f32x4 acc[2][4];
#pragma unroll
  for (int i = 0; i < 2; ++i)
#pragma unroll
    for (int j = 0; j < 4; ++j) {
      f32x4 z = {0.f, 0.f, 0.f, 0.f};
      acc[i][j] = z;
    }

  // fragment byte offsets within a buffer (loop-invariant)
  const int abase = l4 * 1024 + (wr * 32 + l15) * 16;   // A: (l4*64 + row)*16
  const int bbase = l4 * 2048 + (wc * 64 + l15) * 16;   // B: (l4*128 + row)*16

  // staging global bases (per lane), k advances by +k0 elements
  // A: call q=wid -> kslot=wid, row=lane, LDS chunk 64*wid+lane
  const ushort_t* ga  = A  + (size_t)(m0 + lane) * K + wid * 8;
  // B: calls q=2*wid+c -> kslot=wid, row=c*64+lane, LDS chunk 128*wid+c*64+lane
  const ushort_t* gb0 = Bt + (size_t)(n0 + lane) * K + wid * 8;
  const ushort_t* gb1 = Bt + (size_t)(n0 + 64 + lane) * K + wid * 8;

  const int nt = (kend - kbeg) >> 5;

  // prologue: stage tile 0 into buffer 0
  GLOAD(ga + kbeg, As + wid * 512);
  GLOAD(gb0 + kbeg, Bs + (wid * 2) * 512);
  GLOAD(gb1 + kbeg, Bs + (wid * 2 + 1) * 512);
  __syncthreads();   // drains vmcnt -> tile 0 resident

  for (int tt = 0; tt < nt; ++tt) {
    short* Ac = As + (tt & 1) * 2048;
    short* Bc = Bs + (tt & 1) * 4096;
    // issue next tile's DMA into the other buffer (flies under MFMA)
    if (tt + 1 < nt) {
      const int kn = kbeg + (tt + 1) * 32;
      short* An = As + ((tt + 1) & 1) * 2048;
      short* Bn = Bs + ((tt + 1) & 1) * 4096;
      GLOAD(ga + kn, An + wid * 512);
      GLOAD(gb0 + kn, Bn + (wid * 2) * 512);
      GLOAD(gb1 + kn, Bn + (wid * 2 + 1) * 512);
    }
    // fragments + MFMA on current tile
    short8 a0 = *(const short8*)((const char*)Ac + abase);
    short8 a1 = *(const short8*)((const char*)Ac + abase + 256);
    short8 b0 = *(const short8*)((const char*)Bc + bbase);
    short8 b1 = *(const short8*)((const char*)Bc + bbase + 256);
    short8 b2 = *(const short8*)((const char*)Bc + bbase + 512);
    short8 b3 = *(const short8*)((const char*)Bc + bbase + 768);
    acc[0][0] = MFMA16(a0, b0, acc[0][0]);
    acc[0][1] = MFMA16(a0, b1, acc[0][1]);
    acc[0][2] = MFMA16(a0, b2, acc[0][2]);
    acc[0][3] = MFMA16(a0, b3, acc[0][3]);
    acc[1][0] = MFMA16(a1, b0, acc[1][0]);
    acc[1][1] = MFMA16(a1, b1, acc[1][1]);
    acc[1][2] = MFMA16(a1, b2, acc[1][2]);
    acc[1][3] = MFMA16(a1, b3, acc[1][3]);
    __syncthreads();   // waits DMA (vmcnt) + all reads of Ac/Bc done
  }

  // epilogue: C row = l4*4 + r, col = l15 (hardware-verified mapping)
#pragma unroll
  for (int ni = 0; ni < 4; ++ni) {
    const int n = n0 + wc * 64 + ni * 16 + l15;
    const float bb = (EPI == 3) ? 0.f : bias[n];
#pragma unroll
    for (int mi = 0; mi < 2; ++mi) {
      const int mbase = m0 + wr * 32 + mi * 16 + l4 * 4;
#pragma unroll
      for (int r = 0; r < 4; ++r) {
        float x = acc[mi][ni][r] + bb;
        const size_t idx = (size_t)(mbase + r) * N + n;
        if (EPI == 0) {
          C16[idx] = rne(x);
        } else if (EPI == 1) {
          x = 0.5f * x * (1.0f + erff(x * 0.70710678118654752f));
          C16[idx] = rne(x);
        } else {
          Cf[idx] = x;
        }
      }
    }
  }
}

// QKV: grid 768 = 3 mats x 16 mtiles x 16 ntiles
__global__ __launch_bounds__(256, 4)
void qkv2_k(const ushort_t* __restrict__ A, const ushort_t* __restrict__ qkvT,
            const float* __restrict__ bq, const float* __restrict__ bk,
            const float* __restrict__ bv, ushort_t* __restrict__ outq) {
  __shared__ __align__(16) short As[2 * 2048];
  __shared__ __align__(16) short Bs[2 * 4096];
  const int id = swz8(blockIdx.x, 768);
  const int mat = id >> 8, r = id & 255;
  const int m0 = ((r >> 4) & 15) * 64, n0 = (r & 15) * 128;
  const ushort_t* W = qkvT + (size_t)mat * DIM * DIM;
  const float* bias = (mat == 0) ? bq : (mat == 1) ? bk : bv;
  ushort_t* out = outq + (size_t)mat * ROWS * DIM;
  gbody<0>(A, W, bias, nullptr, out, DIM, DIM, 0, DIM, m0, n0, As, Bs);
}

// FFN1 (+GELU): grid 1024 = 16 mtiles x 64 ntiles
__global__ __launch_bounds__(256, 4)
void ffn1_k(const ushort_t* __restrict__ A, const ushort_t* __restrict__ w1T,
            const float* __restrict__ b1, ushort_t* __restrict__ ffh) {
  __shared__ __align__(16) short As[2 * 2048];
  __shared__ __align__(16) short Bs[2 * 4096];
  const int id = swz8(blockIdx.x, 1024);
  const int m0 = (id >> 6) * 64, n0 = (id & 63) * 128;
  gbody<1>(A, w1T, b1, nullptr, ffh, FFDIM, DIM, 0, DIM, m0, n0, As, Bs);
}

// FFN2 (raw fp32 partials): grid 1024 = 4 kslices x 16 mtiles x 16 ntiles
__global__ __launch_bounds__(256, 4)
void ffn2_k(const ushort_t* __restrict__ ffh, const ushort_t* __restrict__ w2T,
            float* __restrict__ partial) {
  __shared__ __align__(16) short As[2 * 2048];
  __shared__ __align__(16) short Bs[2 * 4096];
  const int id = swz8(blockIdx.x, 1024);
  const int ks = id >> 8, r = id & 255;
  const int m0 = ((r >> 4) & 15) * 64, n0 = (r & 15) * 128;
  float* Cf = partial + (size_t)ks * ROWS * DIM;
  gbody<3>(ffh, w2T, nullptr, Cf, nullptr, DIM, FFDIM, ks * 2048,
           ks * 2048 + 2048, m0, n0, As, Bs);
}

// ---------------------------------------------------------------------------
// Transpose-convert: src fp32 [R][C] -> dst bf16 [C][R] (RNE). 64x64 tiles.
__global__ __launch_bounds__(256)
void wconvT_kernel(const float* __restrict__ s0, const float* __restrict__ s1,
                   const float* __restrict__ s2, ushort_t* __restrict__ d,
                   int R, int C) {
  const float* src = (blockIdx.z == 0) ? s0 : (blockIdx.z == 1) ? s1 : s2;
  ushort_t* dst = d + (size_t)blockIdx.z * R * C;
  __shared__ float tl[64][65];
  const int r0 = blockIdx.y * 64, c0 = blockIdx.x * 64;
  const int tr = threadIdx.x >> 4, tc = threadIdx.x & 15;
#pragma unroll
  for (int i = 0; i < 4; ++i) {
    const int r = tr + i * 16;
    float4 v = *(const float4*)&src[(size_t)(r0 + r) * C + c0 + tc * 4];
    tl[r][tc * 4 + 0] = v.x; tl[r][tc * 4 + 1] = v.y;
    tl[r][tc * 4 + 2] = v.z; tl[r][tc * 4 + 3] = v.w;
  }
  __syncthreads();
#pragma unroll
  for (int i = 0; i < 4; ++i) {
    const int c = tr + i * 16;
    ushort4 o;
    o.x = rne(tl[tc * 4 + 0][c]); o.y = rne(tl[tc * 4 + 1][c]);
    o.z = rne(tl[tc * 4 + 2][c]); o.w = rne(tl[tc * 4 + 3][c]);
    *(ushort4*)&dst[(size_t)(c0 + c) * R + r0 + tc * 4] = o;
  }
}

// split-K reduce for FFN2: out = sum_s p[s] + bias + R
__global__ __launch_bounds__(256)
void reduce4_kernel(const float* __restrict__ p, const float* __restrict__ bias,
                    const float* __restrict__ R, float* __restrict__ out) {
  const int idx = blockIdx.x * 256 + threadIdx.x;
  const size_t PS = (size_t)ROWS * DIM / 4;
  const float4* p4 = (const float4*)p;
  float4 s0 = p4[idx], s1 = p4[idx + PS], s2 = p4[idx + 2 * PS], s3 = p4[idx + 3 * PS];
  const int n = (idx & (DIM / 4 - 1)) * 4;
  float4 bi = *(const float4*)&bias[n];
  float4 rr = ((const float4*)R)[idx];
  float4 o;
  o.x = s0.x + s1.x + s2.x + s3.x + bi.x + rr.x;
  o.y = s0.y + s1.y + s2.y + s3.y + bi.y + rr.y;
  o.z = s0.z + s1.z + s2.z + s3.z + bi.z + rr.z;
  o.w = s0.w + s1.w + s2.w + s3.w + bi.w + rr.w;
  ((float4*)out)[idx] = o;
}

// ---------------------------------------------------------------------------
__device__ inline void block_stats(float s, float ss, float& mean, float& rstd) {
#pragma unroll
  for (int off = 32; off; off >>= 1) {
    s  += __shfl_xor(s,  off);
    ss += __shfl_xor(ss, off);
  }
  __shared__ float red[8];
  const int t = threadIdx.x;
  const int w = t >> 6;
  if ((t & 63) == 0) { red[w] = s; red[4 | w] = ss; }
  __syncthreads();
  s  = red[0] + red[1] + red[2] + red[3];
  ss = red[4] + red[5] + red[6] + red[7];
  mean = s * (1.0f / DIM);
  float var = ss * (1.0f / DIM) - mean * mean;
  rstd = 1.0f / sqrtf(var + 1e-5f);
}

// window partition gather + LN1 -> windows fp32 + xbf bf16
__global__ __launch_bounds__(256)
void partition_ln1_kernel(const float* __restrict__ emb,
                          const float* __restrict__ g, const float* __restrict__ be,
                          float* __restrict__ windows, ushort_t* __restrict__ xbf) {
  const int row = blockIdx.x;
  const int b = row >> 6, n = row & 63;
  const int vw = n >> 3, hw = n & 7;
  const int t = threadIdx.x;
  const int d0 = t * 4, d1 = d0 + 1024;

  const int vp0 = d0 >> 8, hp0 = (d0 >> 5) & 7, e0 = d0 & 31;
  const int vp1 = d1 >> 8, hp1 = (d1 >> 5) & 7, e1 = d1 & 31;
  float4 v0 = *(const float4*)&emb[(size_t)(((b*64 + vp0*8 + vw)*64) + hp0*8 + hw)*32 + e0];
  float4 v1 = *(const float4*)&emb[(size_t)(((b*64 + vp1*8 + vw)*64) + hp1*8 + hw)*32 + e1];

  float s  = v0.x+v0.y+v0.z+v0.w + v1.x+v1.y+v1.z+v1.w;
  float ss = v0.x*v0.x+v0.y*v0.y+v0.z*v0.z+v0.w*v0.w
           + v1.x*v1.x+v1.y*v1.y+v1.z*v1.z+v1.w*v1.w;
  float mean, rstd;
  block_stats(s, ss, mean, rstd);

  float* wrow = windows + (size_t)row * DIM;
  *(float4*)&wrow[d0] = v0;
  *(float4*)&wrow[d1] = v1;

  float4 g0 = *(const float4*)&g[d0],  g1 = *(const float4*)&g[d1];
  float4 b0 = *(const float4*)&be[d0], b1 = *(const float4*)&be[d1];
  ushort4 o0, o1;
  o0.x = rne((v0.x-mean)*rstd*g0.x + b0.x); o0.y = rne((v0.y-mean)*rstd*g0.y + b0.y);
  o0.z = rne((v0.z-mean)*rstd*g0.z + b0.z); o0.w = rne((v0.w-mean)*rstd*g0.w + b0.w);
  o1.x = rne((v1.x-mean)*rstd*g1.x + b1.x); o1.y = rne((v1.y-mean)*rstd*g1.y + b1.y);
  o1.z = rne((v1.z-mean)*rstd*g1.z + b1.z); o1.w = rne((v1.w-mean)*rstd*g1.w + b1.w);
  *(ushort4*)&xbf[(size_t)row * DIM + d0] = o0;
  *(ushort4*)&xbf[(size_t)row * DIM + d1] = o1;
}

// LN2: fp32 in -> bf16 out
__global__ __launch_bounds__(256)
void ln_kernel(const float* __restrict__ in, const float* __restrict__ g,
               const float* __restrict__ be, ushort_t* __restrict__ out) {
  const int row = blockIdx.x;
  const int t = threadIdx.x;
  const float* x = in + (size_t)row * DIM;
  const int d0 = t * 4, d1 = d0 + 1024;
  float4 v0 = *(const float4*)&x[d0];
  float4 v1 = *(const float4*)&x[d1];
  float s  = v0.x+v0.y+v0.z+v0.w + v1.x+v1.y+v1.z+v1.w;
  float ss = v0.x*v0.x+v0.y*v0.y+v0.z*v0.z+v0.w*v0.w
           + v1.x*v1.x+v1.y*v1.y+v1.z*v1.z+v1.w*v1.w;
  float mean, rstd;
  block_stats(s, ss, mean, rstd);
  float4 g0 = *(const float4*)&g[d0],  g1 = *(const float4*)&g[d1];
  float4 b0 = *(const float4*)&be[d0], b1 = *(const float4*)&be[d1];
  ushort4 o0, o1;
  o0.x = rne((v0.x-mean)*rstd*g0.x + b0.x); o0.y = rne((v0.y-mean)*rstd*g0.y + b0.y);
  o0.z = rne((v0.z-mean)*rstd*g0.z + b0.z); o0.w = rne((v0.w-mean)*rstd*g0.w + b0.w);
  o1.x = rne((v1.x-mean)*rstd*g1.x + b1.x); o1.y = rne((v1.y-mean)*rstd*g1.y + b1.y);
  o1.z = rne((v1.z-mean)*rstd*g1.z + b1.z); o1.w = rne((v1.w-mean)*rstd*g1.w + b1.w);
  *(ushort4*)&out[(size_t)row * DIM + d0] = o0;
  *(ushort4*)&out[(size_t)row * DIM + d1] = o1;
}

// ---------------------------------------------------------------------------
// Attention: one block per (b, head, query-half). q/k/v bf16; math fp32.
__global__ __launch_bounds__(256)
void attn_kernel(const ushort_t* __restrict__ Q, const ushort_t* __restrict__ K,
                 const ushort_t* __restrict__ V, const float* __restrict__ pb,
                 const float* __restrict__ windows, float* __restrict__ attn_out) {
  __shared__ __align__(16) float kv[NWIN][264];
  __shared__ __align__(16) float qs[32][268];
  __shared__ float att[32][NWIN + 1];
  const int blk = blockIdx.x;
  const int bh = blk >> 1, half = blk & 1;
  const int b = bh >> 3, h = bh & 7;
  const int qbase = half * 32;
  const int t = threadIdx.x;
  const size_t base = (size_t)b * 64 * DIM + (size_t)h * HD;

#pragma unroll
  for (int j = 0; j < 8; ++j) {
    int idx = t + j * 256;
    int m = idx >> 5, c8 = idx & 31;
    uint4 raw = *(const uint4*)&K[base + (size_t)m * DIM + c8 * 8];
    float4 f0 = {bf2f((ushort_t)(raw.x & 0xffff)), bf2f((ushort_t)(raw.x >> 16)),
                 bf2f((ushort_t)(raw.y & 0xffff)), bf2f((ushort_t)(raw.y >> 16))};
    float4 f1 = {bf2f((ushort_t)(raw.z & 0xffff)), bf2f((ushort_t)(raw.z >> 16)),
                 bf2f((ushort_t)(raw.w & 0xffff)), bf2f((ushort_t)(raw.w >> 16))};
    *(float4*)&kv[m][c8 * 8] = f0;
    *(float4*)&kv[m][c8 * 8 + 4] = f1;
  }
#pragma unroll
  for (int j = 0; j < 4; ++j) {
    int idx = t + j * 256;
    int m = idx >> 5, c8 = idx & 31;
    uint4 raw = *(const uint4*)&Q[base + (size_t)(qbase + m) * DIM + c8 * 8];
    float4 f0 = {bf2f((ushort_t)(raw.x & 0xffff)), bf2f((ushort_t)(raw.x >> 16)),
                 bf2f((ushort_t)(raw.y & 0xffff)), bf2f((ushort_t)(raw.y >> 16))};
    float4 f1 = {bf2f((ushort_t)(raw.z & 0xffff)), bf2f((ushort_t)(raw.z >> 16)),
                 bf2f((ushort_t)(raw.w & 0xffff)), bf2f((ushort_t)(raw.w >> 16))};
    *(float4*)&qs[m][c8 * 8] = f0;
    *(float4*)&qs[m][c8 * 8 + 4] = f1;
  }
  __syncthreads();

  {
    const int rp = t & 15;
    const int kg = t >> 4;
    float acc[2][4] = {};
    for (int dg = 0; dg < 64; ++dg) {
      float4 q0 = *(const float4*)&qs[rp][dg * 4];
      float4 q1 = *(const float4*)&qs[rp + 16][dg * 4];
#pragma unroll
      for (int j = 0; j < 4; ++j) {
        float4 kr = *(const float4*)&kv[4 * kg + j][dg * 4];
        acc[0][j] += q0.x * kr.x + q0.y * kr.y + q0.z * kr.z + q0.w * kr.w;
        acc[1][j] += q1.x * kr.x + q1.y * kr.y + q1.z * kr.z + q1.w * kr.w;
      }
    }
    const float scale = 0.022097086912079608f;  // 1/sqrt(2048)
#pragma unroll
    for (int i = 0; i < 2; ++i) {
      const int rl = rp + i * 16;
      const int gr = qbase + rl;
#pragma unroll
      for (int j = 0; j < 4; ++j) {
        const int m = 4 * kg + j;
        float l = acc[i][j] * scale + pb[gr * 64 + m];
        if (m == gr) l = -INFINITY;
        att[rl][m] = l;
      }
    }
  }
  __syncthreads();

#pragma unroll
  for (int j = 0; j < 8; ++j) {
    int idx = t + j * 256;
    int m = idx >> 5, c8 = idx & 31;
    uint4 raw = *(const uint4*)&V[base + (size_t)m * DIM + c8 * 8];
    float4 f0 = {bf2f((ushort_t)(raw.x & 0xffff)), bf2f((ushort_t)(raw.x >> 16)),
                 bf2f((ushort_t)(raw.y & 0xffff)), bf2f((ushort_t)(raw.y >> 16))};
    float4 f1 = {bf2f((ushort_t)(raw.z & 0xffff)), bf2f((ushort_t)(raw.z >> 16)),
                 bf2f((ushort_t)(raw.w & 0xffff)), bf2f((ushort_t)(raw.w >> 16))};
    *(float4*)&kv[m][c8 * 8] = f0;
    *(float4*)&kv[m][c8 * 8 + 4] = f1;
  }
  if (t < 32) {
    float mx = -INFINITY;
#pragma unroll
    for (int m = 0; m < 64; ++m) mx = fmaxf(mx, att[t][m]);
    float sum = 0.f;
#pragma unroll
    for (int m = 0; m < 64; ++m) {
      float e = expf(att[t][m] - mx);
      att[t][m] = e;
      sum += e;
    }
    float inv = 1.0f / sum;
#pragma unroll
    for (int m = 0; m < 64; ++m) att[t][m] *= inv;
  }
  __syncthreads();

  {
    const int dg = t & 63, rg = t >> 6;
    float4 s[8];
#pragma unroll
    for (int i = 0; i < 8; ++i) s[i] = make_float4(0.f, 0.f, 0.f, 0.f);
    for (int m = 0; m < 64; ++m) {
      float4 vr = *(const float4*)&kv[m][dg * 4];
#pragma unroll
      for (int i = 0; i < 8; ++i) {
        const float a = att[rg * 8 + i][m];
        s[i].x = fmaf(a, vr.x, s[i].x); s[i].y = fmaf(a, vr.y, s[i].y);
        s[i].z = fmaf(a, vr.z, s[i].z); s[i].w = fmaf(a, vr.w, s[i].w);
      }
    }
#pragma unroll
    for (int i = 0; i < 8; ++i) {
      const int row = qbase + rg * 8 + i;
      const size_t o = base + (size_t)row * DIM + dg * 4;
      float4 w4 = *(const float4*)&windows[o];
      float4 r;
      r.x = s[i].x + w4.x; r.y = s[i].y + w4.y;
      r.z = s[i].z + w4.z; r.w = s[i].w + w4.w;
      *(float4*)&attn_out[o] = r;
    }
  }
}

// ---------------------------------------------------------------------------
extern "C" void kernel_launch(void* const* d_in, const int* in_sizes, int n_in,
                              void* d_out, int out_size, void* d_ws, size_t ws_size,
                              hipStream_t stream) {
  const float* emb  = (const float*)d_in[0];
  const float* ln1g = (const float*)d_in[1];
  const float* ln1b = (const float*)d_in[2];
  const float* wq   = (const float*)d_in[3];
  const float* bq   = (const float*)d_in[4];
  const float* wk   = (const float*)d_in[5];
  const float* bk   = (const float*)d_in[6];
  const float* wv   = (const float*)d_in[7];
  const float* bv   = (const float*)d_in[8];
  const float* pb   = (const float*)d_in[9];
  const float* ln2g = (const float*)d_in[10];
  const float* ln2b = (const float*)d_in[11];
  const float* w1   = (const float*)d_in[12];
  const float* b1   = (const float*)d_in[13];
  const float* w2   = (const float*)d_in[14];
  const float* b2   = (const float*)d_in[15];
  float* out = (float*)d_out;

  // workspace layout (112 MB), byte offsets in MB:
  //  [0,8)    windows fp32 (dead after attn)
  //  [8,12)   xbf bf16 (LN1 out, then LN2 out)
  //  [12,44)  w1T bf16 [8192][2048]
  //  [44,56)  qb/kb/vb bf16
  //  [56,64)  attn_out fp32
  //  [64,88)  qkvT bf16 (dead after QKV) / [64,96) w2T bf16 (conv after attn)
  //  [96,112) ffh bf16 [1024][8192]
  //  [0,32)   partial fp32 x4 (FFN2 split-K; windows/xbf/w1T dead by then)
  char* W8 = (char*)d_ws;
  float*    windows  = (float*)(W8 + (size_t)0 * MB);
  ushort_t* xbf      = (ushort_t*)(W8 + (size_t)8 * MB);
  ushort_t* w1T      = (ushort_t*)(W8 + (size_t)12 * MB);
  ushort_t* qb       = (ushort_t*)(W8 + (size_t)44 * MB);
  float*    attn_out = (float*)(W8 + (size_t)56 * MB);
  ushort_t* qkvT     = (ushort_t*)(W8 + (size_t)64 * MB);
  ushort_t* w2T      = (ushort_t*)(W8 + (size_t)64 * MB);
  ushort_t* ffh      = (ushort_t*)(W8 + (size_t)96 * MB);
  float*    partial  = (float*)(W8 + (size_t)0 * MB);
  const size_t OFF = (size_t)ROWS * DIM;

  // weight transpose-converts (w2 deferred until qkvT is dead)
  wconvT_kernel<<<dim3(32, 32, 3), 256, 0, stream>>>(wq, wk, wv, qkvT, DIM, DIM);
  wconvT_kernel<<<dim3(128, 32, 1), 256, 0, stream>>>(w1, w1, w1, w1T, DIM, FFDIM);

  partition_ln1_kernel<<<ROWS, 256, 0, stream>>>(emb, ln1g, ln1b, windows, xbf);

  // QKV: 3x [1024,2048]x[2048,2048] -> bf16, 768 blocks (3/CU)
  qkv2_k<<<768, 256, 0, stream>>>(xbf, qkvT, bq, bk, bv, qb);

  attn_kernel<<<16 * NHEAD * 2, 256, 0, stream>>>(qb, qb + OFF, qb + 2 * OFF, pb,
                                                  windows, attn_out);

  wconvT_kernel<<<dim3(32, 128, 1), 256, 0, stream>>>(w2, w2, w2, w2T, FFDIM, DIM);

  ln_kernel<<<ROWS, 256, 0, stream>>>(attn_out, ln2g, ln2b, xbf);

  // FFN1: [1024,2048]x[2048,8192] + GELU -> bf16, 1024 blocks (4/CU)
  ffn1_k<<<1024, 256, 0, stream>>>(xbf, w1T, b1, ffh);
  // FFN2: [1024,8192]x[8192,2048], split-K=4 -> 1024 blocks, fp32 partials
  ffn2_k<<<1024, 256, 0, stream>>>(ffh, w2T, partial);
  // out = sum(partials) + b2 + attn_out
  reduce4_kernel<<<(ROWS * DIM / 4) / 256, 256, 0, stream>>>(partial, b2, attn_out, out);
}